// Round 1
// baseline (1599.565 us; speedup 1.0000x reference)
//
#include <hip/hip_runtime.h>
#include <hip/hip_bf16.h>

typedef __bf16 bf16x8 __attribute__((ext_vector_type(8)));
typedef float f32x4 __attribute__((ext_vector_type(4)));

#define S_DIM 200
#define D_DIM 256
#define SROWS 208          // 13 tiles of 16 rows
#define LSTR 264           // padded LDS row stride (elements): 528B rows, 16B aligned
#define NTHREADS 512

__launch_bounds__(NTHREADS, 1)
__global__ void hba_fused(const float* __restrict__ cate,
                          const float* __restrict__ seq,
                          const int*   __restrict__ mask,
                          const float* __restrict__ W1,
                          const float* __restrict__ b1,
                          const float* __restrict__ W2,
                          const float* __restrict__ b2,
                          float* __restrict__ out)
{
    __shared__ __align__(16) __bf16 sseq[SROWS * LSTR];   // 109824 B
    __shared__ __align__(16) __bf16 w1t[16 * LSTR];       //   8448 B
    __shared__ float scoresS[SROWS];
    __shared__ float cb1v[D_DIM];
    __shared__ float catev[D_DIM];
    __shared__ float part[NTHREADS];

    const int b    = blockIdx.x;
    const int t    = threadIdx.x;
    const int lane = t & 63;
    const int w    = t >> 6;

    // ---------------- phase 1: load seq -> LDS bf16, cate -> LDS ----------------
    if (t >= 256) catev[t - 256] = cate[(size_t)b * 256 + (t - 256)];

    {
        const float4* src = reinterpret_cast<const float4*>(seq + (size_t)b * (S_DIM * D_DIM));
        #pragma unroll
        for (int i = 0; i < 25; ++i) {
            int f = t + i * NTHREADS;             // 0..12799 float4s
            float4 v = src[f];
            int row = f >> 6;                     // 64 float4 per 256-wide row
            int col = (f & 63) << 2;
            union { __bf16 h[4]; uint2 u; } p;
            p.h[0] = (__bf16)v.x; p.h[1] = (__bf16)v.y;
            p.h[2] = (__bf16)v.z; p.h[3] = (__bf16)v.w;
            *reinterpret_cast<uint2*>(&sseq[row * LSTR + col]) = p.u;
        }
    }
    // zero pad rows 200..207 (avoid NaN garbage feeding MFMA)
    for (int i = t; i < 8 * LSTR; i += NTHREADS) sseq[S_DIM * LSTR + i] = (__bf16)0.f;

    __syncthreads();

    // ---------------- cate projection: cb1[e] = cate[b].W2[e] + b2[e] + b1[e] ----------------
    if (t < 256) {
        float acc = b1[t] + b2[t];
        const float* w2r = W2 + t * 256;
        #pragma unroll 4
        for (int k = 0; k < 256; ++k) acc = fmaf(catev[k], w2r[k], acc);
        cb1v[t] = acc;
    }

    // ---------------- GEMM + sigmoid row-sum ----------------
    const int r16  = lane & 15;
    const int quad = lane >> 4;
    const int q8   = quad * 8;

    const int st0  = w;            // s-tile 0..7
    const int st1  = w + 8;        // s-tile 8..12 for waves 0..4
    const bool has2 = (st1 < 13);

    // A fragments held in registers across all 16 n-tiles
    bf16x8 a0[8], a1[8];
    #pragma unroll
    for (int kf = 0; kf < 8; ++kf)
        a0[kf] = *reinterpret_cast<const bf16x8*>(&sseq[(st0 * 16 + r16) * LSTR + kf * 32 + q8]);
    if (has2) {
        #pragma unroll
        for (int kf = 0; kf < 8; ++kf)
            a1[kf] = *reinterpret_cast<const bf16x8*>(&sseq[(st1 * 16 + r16) * LSTR + kf * 32 + q8]);
    }

    float sc0[4] = {0.f, 0.f, 0.f, 0.f};
    float sc1[4] = {0.f, 0.f, 0.f, 0.f};

    for (int nt = 0; nt < 16; ++nt) {
        __syncthreads();   // protect w1t overwrite vs previous iteration's reads
        {
            const int n0 = nt * 16;
            #pragma unroll
            for (int i = 0; i < 2; ++i) {
                int f = t + i * NTHREADS;          // 0..1023 float4s of the 16x256 tile
                int row = f >> 6;
                int col = (f & 63) << 2;
                float4 v = reinterpret_cast<const float4*>(W1)[(n0 + row) * 64 + (f & 63)];
                union { __bf16 h[4]; uint2 u; } p;
                p.h[0] = (__bf16)v.x; p.h[1] = (__bf16)v.y;
                p.h[2] = (__bf16)v.z; p.h[3] = (__bf16)v.w;
                *reinterpret_cast<uint2*>(&w1t[row * LSTR + col]) = p.u;
            }
        }
        __syncthreads();

        f32x4 acc0 = {0.f, 0.f, 0.f, 0.f};
        f32x4 acc1 = {0.f, 0.f, 0.f, 0.f};
        #pragma unroll
        for (int kf = 0; kf < 8; ++kf) {
            bf16x8 bv = *reinterpret_cast<const bf16x8*>(&w1t[r16 * LSTR + kf * 32 + q8]);
            acc0 = __builtin_amdgcn_mfma_f32_16x16x32_bf16(a0[kf], bv, acc0, 0, 0, 0);
            if (has2)
                acc1 = __builtin_amdgcn_mfma_f32_16x16x32_bf16(a1[kf], bv, acc1, 0, 0, 0);
        }

        // epilogue: x = seq_p + cate_p + biases ; accumulate sigmoid(x) over cols
        float basec = cb1v[nt * 16 + r16];     // col = n0 + (lane&15), matches D layout
        #pragma unroll
        for (int r = 0; r < 4; ++r) {
            float x0 = acc0[r] + basec;
            sc0[r] += 1.0f / (1.0f + __expf(-x0));
            if (has2) {
                float x1 = acc1[r] + basec;
                sc1[r] += 1.0f / (1.0f + __expf(-x1));
            }
        }
    }

    // reduce partial sums across the 16 cols (lanes sharing a quad)
    #pragma unroll
    for (int r = 0; r < 4; ++r) {
        float v0 = sc0[r];
        v0 += __shfl_xor(v0, 1); v0 += __shfl_xor(v0, 2);
        v0 += __shfl_xor(v0, 4); v0 += __shfl_xor(v0, 8);
        if (r16 == 0) scoresS[st0 * 16 + quad * 4 + r] = v0;
        if (has2) {
            float v1 = sc1[r];
            v1 += __shfl_xor(v1, 1); v1 += __shfl_xor(v1, 2);
            v1 += __shfl_xor(v1, 4); v1 += __shfl_xor(v1, 8);
            if (r16 == 0) scoresS[st1 * 16 + quad * 4 + r] = v1;
        }
    }
    __syncthreads();

    // ---------------- softmax over s (with mask) ----------------
    float v = -3.0e38f;
    if (t < S_DIM)
        v = mask[(size_t)b * S_DIM + t] ? -1e9f : scoresS[t];

    float m = v;
    #pragma unroll
    for (int off = 32; off > 0; off >>= 1) m = fmaxf(m, __shfl_xor(m, off));
    if (lane == 0) part[w] = m;
    __syncthreads();
    float bm = part[0];
    #pragma unroll
    for (int i = 1; i < 8; ++i) bm = fmaxf(bm, part[i]);

    float e = (t < S_DIM) ? __expf(v - bm) : 0.f;
    float ssum = e;
    #pragma unroll
    for (int off = 32; off > 0; off >>= 1) ssum += __shfl_xor(ssum, off);
    __syncthreads();
    if (lane == 0) part[w] = ssum;
    __syncthreads();
    float tot = 0.f;
    #pragma unroll
    for (int i = 0; i < 8; ++i) tot += part[i];
    float inv = 1.0f / tot;
    __syncthreads();
    if (t < SROWS) scoresS[t] = (t < S_DIM) ? e * inv : 0.f;   // attn weights
    __syncthreads();

    // ---------------- weighted pooling: out[b,d] = sum_s attn[s] * seq[b,s,d] ----------------
    {
        int d    = t & 255;
        int half = t >> 8;
        float acc = 0.f;
        int sbeg = half * 100, send = sbeg + 100;
        #pragma unroll 4
        for (int s2 = sbeg; s2 < send; ++s2)
            acc = fmaf(scoresS[s2], (float)sseq[s2 * LSTR + d], acc);
        part[t] = acc;
    }
    __syncthreads();
    if (t < 256) out[(size_t)b * 256 + t] = part[t] + part[t + 256];
}

extern "C" void kernel_launch(void* const* d_in, const int* in_sizes, int n_in,
                              void* d_out, int out_size, void* d_ws, size_t ws_size,
                              hipStream_t stream) {
    const float* cate = (const float*)d_in[0];
    const float* seq  = (const float*)d_in[1];
    const int*   mask = (const int*)d_in[2];
    const float* W1   = (const float*)d_in[3];
    const float* b1   = (const float*)d_in[4];
    const float* W2   = (const float*)d_in[5];
    const float* b2   = (const float*)d_in[6];
    float* out = (float*)d_out;

    const int B = in_sizes[0] / D_DIM;   // 4096
    hba_fused<<<B, NTHREADS, 0, stream>>>(cate, seq, mask, W1, b1, W2, b2, out);
}